// Round 14
// baseline (1540.340 us; speedup 1.0000x reference)
//
#include <hip/hip_runtime.h>
#include <math.h>

// ---------------------------------------------------------------------------
// SpatialAttentionModel on MI355X.
// R14: e5m2 stream tier, NO builtins / NO conditional macros (R12+R13 both
// silently fell back: __has_builtin gates resolved false and, being
// host/device-divergent, were layout-hazardous anyway). e5m2 == truncated
// f16, decoded with ONE inline-asm v_perm_b32 per f16 pair (assembler-level;
// the inline-asm mechanism is proven since R6). Stream (elems 64..255 of
// each gate row) halves: 384 -> 192 KB/step against the measured
// ~87 B/cyc/CU L2 wall. LDS tier (elems 0..63) stays f16 dot2 vs packed h2l
// (the R11 operand shape, 937us baseline). Encode = plain int ops in k_pre.
// Keeps the Vp-GEMM/pack overlap inside the LSTM launch and the merged k_pre.
// ---------------------------------------------------------------------------

typedef _Float16 h2_t __attribute__((ext_vector_type(2)));

#if __has_builtin(__builtin_amdgcn_fdot2)
#define HAVE_FDOT2 1
#else
#define HAVE_FDOT2 0
#endif

__device__ __forceinline__ float dot2(unsigned w, unsigned h, float acc) {
#if HAVE_FDOT2
  return __builtin_amdgcn_fdot2(__builtin_bit_cast(h2_t, w),
                                __builtin_bit_cast(h2_t, h), acc, false);
#else
  h2_t a = __builtin_bit_cast(h2_t, w);
  h2_t b = __builtin_bit_cast(h2_t, h);
  return acc + (float)a[0] * (float)b[0] + (float)a[1] * (float)b[1];
#endif
}

__device__ __forceinline__ unsigned pack2(float a, float b) {
  h2_t p;
  p[0] = (_Float16)a;
  p[1] = (_Float16)b;
  return __builtin_bit_cast(unsigned, p);
}

__device__ __forceinline__ float sigmoid_f(float x) {
  return __builtin_amdgcn_rcpf(1.f + __expf(-x));
}
__device__ __forceinline__ float tanh_f(float x) {
  return 1.f - 2.f * __builtin_amdgcn_rcpf(1.f + __expf(2.f * x));
}

// e5m2 byte b -> f16 (b<<8) is exact (same exponent bias). perm builds a
// packed f16 pair from bytes (0,1) or (2,3) of w in one v_perm_b32.
// VOP3 operand rules: src1 = inline 0, selector in SGPR (wave-uniform).
__device__ __forceinline__ unsigned perm_lo(unsigned w, unsigned sel) {
  unsigned r;
  asm("v_perm_b32 %0, %1, 0, %2" : "=v"(r) : "v"(w), "s"(sel));
  return r;
}

// e5m2 encode: f32 -> f16 (RNE) -> high byte, round-half-up on low 8 bits
// (+0x80 carry rounds mantissa overflow into the exponent correctly).
__device__ __forceinline__ unsigned enc_e5m2_4(float a, float b, float c,
                                               float d) {
  unsigned r = 0;
  unsigned short h;
  h = __builtin_bit_cast(unsigned short, (_Float16)a);
  r |= (((unsigned)h + 0x80u) >> 8) & 0xFFu;
  h = __builtin_bit_cast(unsigned short, (_Float16)b);
  r |= ((((unsigned)h + 0x80u) >> 8) & 0xFFu) << 8;
  h = __builtin_bit_cast(unsigned short, (_Float16)c);
  r |= ((((unsigned)h + 0x80u) >> 8) & 0xFFu) << 16;
  h = __builtin_bit_cast(unsigned short, (_Float16)d);
  r |= ((((unsigned)h + 0x80u) >> 8) & 0xFFu) << 24;
  return r;
}

// Fixed layout constants (identical in host and device passes).
#define STREAM_DW 49152           // uint4[12][1024] e5m2: elems 64..255
#define PACK_DW (32768 + STREAM_DW)
#define NPACK (PACK_DW / 256)     // 320

// ---------------------------------------------------------------------------
// k_pre: merged pre-work. Block ranges:
//  [0, NPACK)              : Whh pack (f16 LDS tier + e5m2 stream tier)
//  [NPACK, +64)            : W_cn -> packed f16 pairs
//  [NPACK+64, +7936)       : xg (gate-major)
//  [NPACK+8000, +64)       : h0/c0 init
__global__ __launch_bounds__(256) void k_pre(
    const float* __restrict__ Whh, unsigned* __restrict__ wlds_pack,
    unsigned* __restrict__ wst, const float* __restrict__ W_cn,
    unsigned* __restrict__ wcn_h2, const float* __restrict__ gaze,
    const float* __restrict__ Wih, const float* __restrict__ bih,
    const float* __restrict__ bhh, float* __restrict__ xg,
    const float* __restrict__ Wh1, const float* __restrict__ bh1,
    const float* __restrict__ Wh2, const float* __restrict__ bh2,
    const float* __restrict__ Wc1, const float* __restrict__ bc1,
    const float* __restrict__ Wc2, const float* __restrict__ bc2,
    float* __restrict__ HH, float* __restrict__ c0) {
  const int bid = blockIdx.x;
  const int tid = threadIdx.x;
  if (bid < NPACK) {
    const int idx = bid * 256 + tid;
    if (idx < 32768) {
      const int row = idx >> 5, pair = idx & 31;
      wlds_pack[idx] =
          pack2(Whh[row * 256 + 2 * pair], Whh[row * 256 + 2 * pair + 1]);
    } else {
      const int rel = idx - 32768;  // < 49152
      const int m = rel >> 12, row = (rel >> 2) & 1023, d = rel & 3;
      const float* wr = Whh + row * 256 + 64 + 16 * m + 4 * d;
      wst[rel] = enc_e5m2_4(wr[0], wr[1], wr[2], wr[3]);
    }
  } else if (bid < NPACK + 64) {
    const int i = (bid - NPACK) * 256 + tid;  // < 16384
    wcn_h2[i] = pack2(W_cn[2 * i], W_cn[2 * i + 1]);
  } else if (bid < NPACK + 64 + 7936) {
    const int idx = (bid - NPACK - 64) * 256 + tid;
    if (idx < 31 * 64 * 1024) {
      const int j = idx & 1023;
      const int b = (idx >> 10) & 63;
      const int t = idx >> 16;
      const float* gz = gaze + (b * 32 + t) * 3;
      xg[idx] = gz[0] * Wih[j * 3 + 0] + gz[1] * Wih[j * 3 + 1] +
                gz[2] * Wih[j * 3 + 2] + bih[j] + bhh[j];
    }
  } else {
    const int b = bid - NPACK - 64 - 7936;  // < 64
    __shared__ float mg[3];
    __shared__ float t1h[256], t1c[256];
    if (tid < 3) {
      float s = 0.f;
      for (int t = 0; t < 32; t++) s += gaze[(b * 32 + t) * 3 + tid];
      mg[tid] = s * (1.f / 32.f);
    }
    __syncthreads();
    {
      float a = mg[0] * Wh1[tid * 3 + 0] + mg[1] * Wh1[tid * 3 + 1] +
                mg[2] * Wh1[tid * 3 + 2] + bh1[tid];
      t1h[tid] = tanhf(a);
      float c = mg[0] * Wc1[tid * 3 + 0] + mg[1] * Wc1[tid * 3 + 1] +
                mg[2] * Wc1[tid * 3 + 2] + bc1[tid];
      t1c[tid] = tanhf(c);
    }
    __syncthreads();
    float s1 = bh2[tid], s2 = bc2[tid];
    for (int k = 0; k < 256; k++) {
      s1 += t1h[k] * Wh2[tid * 256 + k];
      s2 += t1c[k] * Wc2[tid * 256 + k];
    }
    HH[b * 256 + tid] = tanhf(tanhf(s1));
    c0[b * 256 + tid] = tanhf(tanhf(s2));
  }
}

// ---------------------------------------------------------------------------
// Fused kernel (1024 threads/block):
//  blocks [0,64)        : LSTM chains (R11 structure; e5m2 stream)
//  blocks [64,64+nvp)   : Vp GEMM tiles
//  blocks [64+nvp,+17)  : MLP/W_lh weight packs
__global__ __launch_bounds__(1024) void k_fused(
    const float* __restrict__ xg, const unsigned* __restrict__ wst,
    const unsigned* __restrict__ wlds_pack, const float* __restrict__ c0,
    float* __restrict__ HH, const float* __restrict__ cnn,
    const unsigned* __restrict__ wcn_h2, const float* __restrict__ bcn,
    unsigned* __restrict__ Vp, int nvp, const float* __restrict__ Wm1,
    unsigned* __restrict__ wm1d, const float* __restrict__ Wm2,
    unsigned* __restrict__ wm2d, const float* __restrict__ Wm3,
    unsigned* __restrict__ wm3d, const float* __restrict__ Wlh,
    unsigned* __restrict__ wlhd) {
  const int bid = blockIdx.x;
  const int tid = threadIdx.x;
  __shared__ __align__(16) unsigned smem[38016];  // 152064 B

  if (bid < 64) {
    // ================= LSTM path =================
    const int b = bid;
    unsigned* wlds = smem;                    // [1024*36]
    float* actl = (float*)(smem + 36864);     // [1024]
    unsigned* h2l = smem + 36864 + 1024;      // [128] packed f16, elems 0..255

    for (int i = tid; i < 1024 * 32; i += 1024) {
      const int row = i >> 5, p = i & 31;
      wlds[row * 36 + p] = wlds_pack[i];
    }

    float cst = (tid < 256) ? c0[b * 256 + tid] : 0.f;
    if (tid < 256) ((_Float16*)h2l)[tid] = (_Float16)HH[b * 256 + tid];
    __syncthreads();

    const unsigned* wA = &wlds[tid * 36];
    const uint4* wstp = (const uint4*)wst + tid;
    const bool is_g = (tid >= 512) & (tid < 768);  // wave-uniform
    const unsigned selLo = 0x050C040Cu;  // -> [0, b0, 0, b1] = f16 pair
    const unsigned selHi = 0x070C060Cu;  // -> [0, b2, 0, b3] = f16 pair
    float hval = 0.f;

    for (int frame = 0; frame < 32; frame++) {
      const int L = frame ? frame : 1;
      for (int t = 0; t < L; t++) {
        const float xgv = xg[(t * 64 + b) * 1024 + tid];
        float ga0 = 0.f, ga1 = 0.f;
        // ---- LDS f16 tier: elems 0..63 ----
#pragma unroll
        for (int q = 0; q < 8; q++) {
          const uint4 h4 = *(const uint4*)&h2l[4 * q];
          const uint4 a4 = *(const uint4*)&wA[4 * q];
          if ((q & 1) == 0) {
            ga0 = dot2(a4.x, h4.x, ga0);
            ga0 = dot2(a4.y, h4.y, ga0);
            ga0 = dot2(a4.z, h4.z, ga0);
            ga0 = dot2(a4.w, h4.w, ga0);
          } else {
            ga1 = dot2(a4.x, h4.x, ga1);
            ga1 = dot2(a4.y, h4.y, ga1);
            ga1 = dot2(a4.z, h4.z, ga1);
            ga1 = dot2(a4.w, h4.w, ga1);
          }
        }
        // ---- streamed e5m2 tier: elems 64..255, 12 dwordx4 loads ----
#pragma unroll
        for (int m = 0; m < 12; m++) {
          const uint4 wq = wstp[m << 10];
          const uint4 ha = *(const uint4*)&h2l[32 + 8 * m];
          const uint4 hb = *(const uint4*)&h2l[36 + 8 * m];
          ga0 = dot2(perm_lo(wq.x, selLo), ha.x, ga0);
          ga1 = dot2(perm_lo(wq.x, selHi), ha.y, ga1);
          ga0 = dot2(perm_lo(wq.y, selLo), ha.z, ga0);
          ga1 = dot2(perm_lo(wq.y, selHi), ha.w, ga1);
          ga0 = dot2(perm_lo(wq.z, selLo), hb.x, ga0);
          ga1 = dot2(perm_lo(wq.z, selHi), hb.y, ga1);
          ga0 = dot2(perm_lo(wq.w, selLo), hb.z, ga0);
          ga1 = dot2(perm_lo(wq.w, selHi), hb.w, ga1);
        }
        const float g = ga0 + ga1 + xgv;
        const float act = is_g ? tanh_f(g) : sigmoid_f(g);
        actl[tid] = act;
        __syncthreads();  // B1: h2l reads done; acts visible
        if (tid < 256) {
          const float i_ = actl[tid];
          const float f_ = actl[256 + tid];
          const float g_ = actl[512 + tid];
          const float o_ = actl[768 + tid];
          cst = f_ * cst + i_ * g_;
          hval = o_ * tanh_f(cst);
          ((_Float16*)h2l)[tid] = (_Float16)hval;
        }
        __syncthreads();  // B2: h2l ready for next step
      }
      if (tid < 256) HH[((frame + 1) * 64 + b) * 256 + tid] = hval;
    }
  } else if (bid < 64 + nvp) {
    // ================= Vp GEMM path (1024 threads) =================
    const int vb = bid - 64;  // < 576
    const int i = vb / 18, rt = vb - 18 * i;
    const int r0 = rt * 128;
    unsigned* As = smem;                   // 128*132
    unsigned* Bs = smem + 16896;           // 128*132
    float* bcs = (float*)(smem + 33792);   // 128

    for (int idx = tid; idx < 128 * 128; idx += 1024) {
      const int r = idx >> 7, kp = idx & 127;
      const int R = r0 + r;
      const int b = R / 36, g = R - b * 36;
      const float* src = cnn + (((size_t)b * 32 + i) * 36 + g) * 256 + 2 * kp;
      As[r * 132 + kp] = pack2(src[0], src[1]);
    }
    for (int idx = tid; idx < 128 * 128; idx += 1024) {
      const int o = idx >> 7, kp = idx & 127;
      Bs[o * 132 + kp] = wcn_h2[o * 128 + kp];
    }
    if (tid < 128) bcs[tid] = bcn[tid];
    __syncthreads();

    const int ry = tid >> 4, px = tid & 15;  // ry<64
    float acc[2][8];
#pragma unroll
    for (int k = 0; k < 2; k++)
#pragma unroll
      for (int m = 0; m < 8; m++)
        acc[k][m] = bcs[32 * (m >> 1) + 2 * px + (m & 1)];
    for (int kb = 0; kb < 32; kb++) {
      uint4 a4[2], b4[8];
#pragma unroll
      for (int k = 0; k < 2; k++)
        a4[k] = *(const uint4*)&As[(64 * k + ry) * 132 + 4 * kb];
#pragma unroll
      for (int m = 0; m < 8; m++)
        b4[m] = *(const uint4*)&Bs[(32 * (m >> 1) + 2 * px + (m & 1)) * 132 + 4 * kb];
#pragma unroll
      for (int k = 0; k < 2; k++)
#pragma unroll
        for (int m = 0; m < 8; m++) {
          acc[k][m] = dot2(a4[k].x, b4[m].x, acc[k][m]);
          acc[k][m] = dot2(a4[k].y, b4[m].y, acc[k][m]);
          acc[k][m] = dot2(a4[k].z, b4[m].z, acc[k][m]);
          acc[k][m] = dot2(a4[k].w, b4[m].w, acc[k][m]);
        }
    }
#pragma unroll
    for (int k = 0; k < 2; k++) {
      const int R = r0 + 64 * k + ry;
#pragma unroll
      for (int jj = 0; jj < 4; jj++)
        Vp[((size_t)i * 2304 + R) * 64 + 16 * jj + px] =
            pack2(acc[k][2 * jj], acc[k][2 * jj + 1]);
    }
  } else {
    // ================= pack path (17 blocks) =================
    const int pb = bid - 64 - nvp;
    if (pb < 8) {
      const int base = pb * 16384;
      for (int j = tid; j < 16384; j += 1024)
        wm1d[base + j] = pack2(Wm1[2 * (base + j)], Wm1[2 * (base + j) + 1]);
    } else if (pb < 16) {
      const int base = (pb - 8) * 16384;
      for (int j = tid; j < 16384; j += 1024)
        wm2d[base + j] = pack2(Wm2[2 * (base + j)], Wm2[2 * (base + j) + 1]);
    } else {
      for (int j = tid; j < 1536; j += 1024)
        wm3d[j] = pack2(Wm3[2 * j], Wm3[2 * j + 1]);
      for (int j = tid; j < 16384; j += 1024)
        wlhd[j] = pack2(Wlh[2 * j], Wlh[2 * j + 1]);
    }
  }
}

// z finish: z[b,g] = sum_p w[p]*tanh(Hl[i,b,p] + Vp[i,R,p]).
__global__ void k_zfin(const unsigned* __restrict__ Vp,
                       const float* __restrict__ Hl,
                       const float* __restrict__ wwt,
                       float* __restrict__ zbuf) {
  const int bid = blockIdx.x;  // 576
  const int i = bid / 18, rt = bid - 18 * i;
  const int r0 = rt * 128;
  const int tid = threadIdx.x;  // 256
  __shared__ float Hls[5 * 128];
  __shared__ float wws[128];
  __shared__ float zpart[128 * 16];
  const int bmin = r0 / 36;
  for (int idx = tid; idx < 5 * 128; idx += 256) {
    const int bb = bmin + (idx >> 7);
    if (bb < 64) Hls[idx] = Hl[(i * 64 + bb) * 128 + (idx & 127)];
  }
  if (tid < 128) wws[tid] = wwt[tid];
  __syncthreads();
  const int ry = tid >> 4, px = tid & 15;
#pragma unroll
  for (int k = 0; k < 8; k++) {
    const int r = 16 * k + ry;
    const int R = r0 + r;
    const int b = R / 36;
    const unsigned* vr = Vp + ((size_t)i * 2304 + R) * 64;
    const float* Hr = &Hls[(b - bmin) * 128];
    float z = 0.f;
#pragma unroll
    for (int jj = 0; jj < 4; jj++) {
      const int pp = 16 * jj + px;
      const h2_t pr = __builtin_bit_cast(h2_t, vr[pp]);
      z += wws[2 * pp] * tanh_f(Hr[2 * pp] + (float)pr[0]);
      z += wws[2 * pp + 1] * tanh_f(Hr[2 * pp + 1] + (float)pr[1]);
    }
    zpart[r * 16 + px] = z;
  }
  __syncthreads();
  if (tid < 128) {
    float z = 0.f;
#pragma unroll
    for (int x = 0; x < 16; x++) z += zpart[tid * 16 + x];
    const int R = r0 + tid;
    const int b = R / 36, g = R - b * 36;
    zbuf[(i * 64 + b) * 36 + g] = z;
  }
}

// Hl[i][b][p] = HH[i][b]·W_lh[p] + b_lh[p].
__global__ void k_hl(const float* __restrict__ HH,
                     const unsigned* __restrict__ wlh_h2,
                     const float* __restrict__ blh, float* __restrict__ Hl) {
  const int i = blockIdx.x;
  const int tid = threadIdx.x;  // 256
  __shared__ __align__(16) unsigned Ah[64 * 132];
  __shared__ __align__(16) unsigned Bh[128 * 132];
  for (int idx = tid; idx < 64 * 128; idx += 256) {
    const int r = idx >> 7, kp = idx & 127;
    const float* s = HH + ((size_t)(i * 64 + r)) * 256 + 2 * kp;
    Ah[r * 132 + kp] = pack2(s[0], s[1]);
  }
  for (int idx = tid; idx < 128 * 128; idx += 256) {
    const int o = idx >> 7, kp = idx & 127;
    Bh[o * 132 + kp] = wlh_h2[o * 128 + kp];
  }
  __syncthreads();
  const int ry = tid >> 4, px = tid & 15;
  float acc[4][8];
#pragma unroll
  for (int k = 0; k < 4; k++)
#pragma unroll
    for (int j = 0; j < 8; j++) acc[k][j] = 0.f;
  for (int kb = 0; kb < 32; kb++) {
    uint4 a4[4], b4[8];
#pragma unroll
    for (int k = 0; k < 4; k++) a4[k] = *(const uint4*)&Ah[(16 * k + ry) * 132 + 4 * kb];
#pragma unroll
    for (int j = 0; j < 8; j++) b4[j] = *(const uint4*)&Bh[(16 * j + px) * 132 + 4 * kb];
#pragma unroll
    for (int k = 0; k < 4; k++)
#pragma unroll
      for (int j = 0; j < 8; j++) {
        acc[k][j] = dot2(a4[k].x, b4[j].x, acc[k][j]);
        acc[k][j] = dot2(a4[k].y, b4[j].y, acc[k][j]);
        acc[k][j] = dot2(a4[k].z, b4[j].z, acc[k][j]);
        acc[k][j] = dot2(a4[k].w, b4[j].w, acc[k][j]);
      }
  }
#pragma unroll
  for (int k = 0; k < 4; k++)
#pragma unroll
    for (int j = 0; j < 8; j++)
      Hl[(i * 64 + 16 * k + ry) * 128 + 16 * j + px] = acc[k][j] + blh[16 * j + px];
}

// Fallback (small ws): fused Vp GEMM + z.
__global__ void k_att_z(const float* __restrict__ cnn,
                        const unsigned* __restrict__ wcn_h2,
                        const float* __restrict__ bcn,
                        const float* __restrict__ Hl,
                        const float* __restrict__ wwt,
                        float* __restrict__ zbuf) {
  const int bid = blockIdx.x;  // 576
  const int i = bid / 18, rt = bid - 18 * i;
  const int tid = threadIdx.x;  // 256
  const int r0 = rt * 128;
  __shared__ __align__(16) unsigned As[128 * 132];
  __shared__ __align__(16) unsigned Bs[128 * 132];
  __shared__ float zpart[128 * 16];
  __shared__ float Hls[5 * 128];
  __shared__ float wws[128];
  __shared__ float bcs[128];

  for (int idx = tid; idx < 128 * 128; idx += 256) {
    const int r = idx >> 7, kp = idx & 127;
    const int R = r0 + r;
    const int b = R / 36, g = R - b * 36;
    const float* src = cnn + (((size_t)b * 32 + i) * 36 + g) * 256 + 2 * kp;
    As[r * 132 + kp] = pack2(src[0], src[1]);
  }
  for (int idx = tid; idx < 128 * 128; idx += 256) {
    const int o = idx >> 7, kp = idx & 127;
    Bs[o * 132 + kp] = wcn_h2[o * 128 + kp];
  }
  const int bmin = r0 / 36;
  for (int idx = tid; idx < 5 * 128; idx += 256) {
    const int bb = bmin + (idx >> 7);
    if (bb < 64) Hls[idx] = Hl[(i * 64 + bb) * 128 + (idx & 127)];
  }
  if (tid < 128) {
    wws[tid] = wwt[tid];
    bcs[tid] = bcn[tid];
  }
  __syncthreads();

  const int ry = tid >> 4, px = tid & 15;
  float acc[8][8];
#pragma unroll
  for (int k = 0; k < 8; k++)
#pragma unroll
    for (int j = 0; j < 8; j++) acc[k][j] = bcs[16 * j + px];
  for (int kb = 0; kb < 32; kb++) {
    uint4 a4[8], b4[8];
#pragma unroll
    for (int k = 0; k < 8; k++) a4[k] = *(const uint4*)&As[(16 * k + ry) * 132 + 4 * kb];
#pragma unroll
    for (int j = 0; j < 8; j++) b4[j] = *(const uint4*)&Bs[(16 * j + px) * 132 + 4 * kb];
#pragma unroll
    for (int k = 0; k < 8; k++)
#pragma unroll
      for (int j = 0; j < 8; j++) {
        acc[k][j] = dot2(a4[k].x, b4[j].x, acc[k][j]);
        acc[k][j] = dot2(a4[k].y, b4[j].y, acc[k][j]);
        acc[k][j] = dot2(a4[k].z, b4[j].z, acc[k][j]);
        acc[k][j] = dot2(a4[k].w, b4[j].w, acc[k][j]);
      }
  }
#pragma unroll
  for (int k = 0; k < 8; k++) {
    const int r = 16 * k + ry;
    const int R = r0 + r;
    const int b = R / 36;
    const float* HlRow = &Hls[(b - bmin) * 128];
    float zp = 0.f;
#pragma unroll
    for (int j = 0; j < 8; j++) {
      const int po = 16 * j + px;
      zp += wws[po] * tanh_f(HlRow[po] + acc[k][j]);
    }
    zpart[r * 16 + px] = zp;
  }
  __syncthreads();
  if (tid < 128) {
    float z = 0.f;
#pragma unroll
    for (int x = 0; x < 16; x++) z += zpart[tid * 16 + x];
    const int R = r0 + tid;
    const int b = R / 36, g = R - b * 36;
    zbuf[(i * 64 + b) * 36 + g] = z;
  }
}

// Scrambled softmax + weighted V sum; builds fc = [spatial_feat | h_next].
__global__ void k_att_sf(const float* __restrict__ cnn,
                         const float* __restrict__ zbuf,
                         const float* __restrict__ HH,
                         float* __restrict__ fc) {
  const int bid = blockIdx.x;  // 2048
  const int i = bid >> 6, b = bid & 63;
  const int tid = threadIdx.x;  // 256
  __shared__ float zl[36];
  __shared__ float el[40];
  __shared__ float red[1];
  if (tid < 36) {
    const int idx = b * 36 + tid;
    zl[tid] = zbuf[(i * 64 + (idx & 63)) * 36 + (idx >> 6)];
  }
  __syncthreads();
  if (tid == 0) {
    float m = zl[0];
    for (int g = 1; g < 36; g++) m = fmaxf(m, zl[g]);
    float s = 0.f;
    for (int g = 0; g < 36; g++) {
      const float e = __expf(zl[g] - m);
      el[g] = e;
      s += e;
    }
    red[0] = 1.f / s;
  }
  __syncthreads();
  const float inv = red[0];
  float accv = 0.f;
  const float* Vb = cnn + (((size_t)b * 32 + i) * 36) * 256 + tid;
#pragma unroll 4
  for (int g = 0; g < 36; g++) accv += el[g] * Vb[g * 256];
  fc[(size_t)bid * 512 + tid] = accv * inv;
  fc[(size_t)bid * 512 + 256 + tid] = HH[((i + 1) * 64 + b) * 256 + tid];
}

// MLP layers 1/2.
template <int SRCMODE>
__global__ void k_mlp(const void* __restrict__ src,
                      const unsigned* __restrict__ wh2,
                      const float* __restrict__ bias,
                      unsigned* __restrict__ dst) {
  const int bid = blockIdx.x;  // 128
  const int nb = bid >> 2, ob = bid & 3;
  const int n0 = nb * 64, o0 = ob * 128;
  const int tid = threadIdx.x;
  __shared__ __align__(16) unsigned As[64 * 132];
  __shared__ __align__(16) unsigned Bs[128 * 132];
  const int ry = tid >> 4, px = tid & 15;
  float acc[4][8];
#pragma unroll
  for (int k = 0; k < 4; k++)
#pragma unroll
    for (int m = 0; m < 8; m++)
      acc[k][m] = bias[o0 + 32 * (m >> 1) + 2 * px + (m & 1)];
  for (int kc = 0; kc < 2; kc++) {
    __syncthreads();
    for (int idx = tid; idx < 64 * 128; idx += 256) {
      const int r = idx >> 7, kp = idx & 127;
      if (SRCMODE == 0) {
        const float* s = (const float*)src + ((size_t)(n0 + r)) * 512 + kc * 256 + 2 * kp;
        As[r * 132 + kp] = pack2(s[0], s[1]);
      } else {
        As[r * 132 + kp] = ((const unsigned*)src)[((size_t)(n0 + r)) * 256 + kc * 128 + kp];
      }
    }
    for (int idx = tid; idx < 128 * 128; idx += 256) {
      const int o = idx >> 7, kp = idx & 127;
      Bs[o * 132 + kp] = wh2[((size_t)(o0 + o)) * 256 + kc * 128 + kp];
    }
    __syncthreads();
    for (int kb = 0; kb < 32; kb++) {
      uint4 a4[4], b4[8];
#pragma unroll
      for (int k = 0; k < 4; k++)
        a4[k] = *(const uint4*)&As[(16 * k + ry) * 132 + 4 * kb];
#pragma unroll
      for (int m = 0; m < 8; m++)
        b4[m] = *(const uint4*)&Bs[(32 * (m >> 1) + 2 * px + (m & 1)) * 132 + 4 * kb];
#pragma unroll
      for (int k = 0; k < 4; k++)
#pragma unroll
        for (int m = 0; m < 8; m++) {
          acc[k][m] = dot2(a4[k].x, b4[m].x, acc[k][m]);
          acc[k][m] = dot2(a4[k].y, b4[m].y, acc[k][m]);
          acc[k][m] = dot2(a4[k].z, b4[m].z, acc[k][m]);
          acc[k][m] = dot2(a4[k].w, b4[m].w, acc[k][m]);
        }
    }
  }
#pragma unroll
  for (int k = 0; k < 4; k++) {
    const int n = n0 + 16 * k + ry;
#pragma unroll
    for (int j = 0; j < 4; j++)
      dst[(size_t)n * 256 + (o0 >> 1) + 16 * j + px] =
          pack2(acc[k][2 * j], acc[k][2 * j + 1]);
  }
}

// Final layer: (2048,512) -> 6 classes.
__global__ void k_mlp3(const unsigned* __restrict__ y2h2,
                       const unsigned* __restrict__ wm3h2,
                       const float* __restrict__ bm3,
                       float* __restrict__ out) {
  const int nb = blockIdx.x;  // 32
  const int tid = threadIdx.x;
  __shared__ __align__(16) unsigned Ys[64 * 256];
  __shared__ __align__(16) unsigned Ws[6 * 256];
  for (int idx = tid; idx < 64 * 256; idx += 256)
    Ys[idx] = y2h2[(size_t)nb * 64 * 256 + idx];
  for (int idx = tid; idx < 6 * 256; idx += 256) Ws[idx] = wm3h2[idx];
  __syncthreads();
  for (int u = 0; u < 2; u++) {
    const int idx = tid + u * 256;
    if (idx < 384) {
      const int nl = idx / 6, c = idx - 6 * nl;
      float a0 = 0.f, a1 = 0.f;
#pragma unroll
      for (int kq = 0; kq < 64; kq++) {
        const uint4 y4 = *(const uint4*)&Ys[nl * 256 + 4 * kq];
        const uint4 w4 = *(const uint4*)&Ws[c * 256 + 4 * kq];
        a0 = dot2(y4.x, w4.x, a0);
        a1 = dot2(y4.y, w4.y, a1);
        a0 = dot2(y4.z, w4.z, a0);
        a1 = dot2(y4.w, w4.w, a1);
      }
      out[(size_t)(nb * 64 + nl) * 6 + c] = a0 + a1 + bm3[c];
    }
  }
}

// ---------------------------------------------------------------------------
extern "C" void kernel_launch(void* const* d_in, const int* in_sizes, int n_in,
                              void* d_out, int out_size, void* d_ws,
                              size_t ws_size, hipStream_t stream) {
  (void)in_sizes; (void)n_in; (void)out_size;
  const float* cnn  = (const float*)d_in[0];
  const float* gaze = (const float*)d_in[1];
  const float* W_lh = (const float*)d_in[2];
  const float* b_lh = (const float*)d_in[3];
  const float* W_cn = (const float*)d_in[4];
  const float* b_cn = (const float*)d_in[5];
  const float* w_wt = (const float*)d_in[6];
  const float* Wih  = (const float*)d_in[7];
  const float* Whh  = (const float*)d_in[8];
  const float* bih  = (const float*)d_in[9];
  const float* bhh  = (const float*)d_in[10];
  const float* Wh1  = (const float*)d_in[11];
  const float* bh1  = (const float*)d_in[12];
  const float* Wh2  = (const float*)d_in[13];
  const float* bh2  = (const float*)d_in[14];
  const float* Wc1  = (const float*)d_in[15];
  const float* bc1  = (const float*)d_in[16];
  const float* Wc2  = (const float*)d_in[17];
  const float* bc2  = (const float*)d_in[18];
  const float* Wm1  = (const float*)d_in[19];
  const float* bm1  = (const float*)d_in[20];
  const float* Wm2  = (const float*)d_in[21];
  const float* bm2  = (const float*)d_in[22];
  const float* Wm3  = (const float*)d_in[23];
  const float* bm3  = (const float*)d_in[24];
  float* out = (float*)d_out;

  unsigned* W = (unsigned*)d_ws;
  float* Wf = (float*)d_ws;
  // workspace offsets in dwords (wst region keeps the larger legacy size)
  const size_t O_xg  = 0;                    // [31][64][1024] f32
  const size_t O_wl  = 2031616;              // [1024][32]  u32
  const size_t O_wst = O_wl + 32768;         // stream tier (49152 used)
  const size_t O_HH  = O_wst + 98304;        // [33][64][256] f32
  const size_t O_c0  = O_HH + 540672;        // [64][256]   f32
  const size_t O_Hl  = O_c0 + 16384;         // [32][64][128] f32
  const size_t O_z   = O_Hl + 262144;        // [32][64][36] f32
  const size_t O_fc  = O_z + 73728;          // [2048][512] f32
  const size_t O_y1  = O_fc + 1048576;       // [2048][256] u32
  const size_t O_y2  = O_y1 + 524288;        // [2048][256] u32
  const size_t O_wcn = O_y2 + 524288;        // [128][128]  u32
  const size_t O_wlh = O_wcn + 16384;        // [128][128]  u32
  const size_t O_wm1 = O_wlh + 16384;        // [512][256]  u32
  const size_t O_wm2 = O_wm1 + 131072;
  const size_t O_wm3 = O_wm2 + 131072;       // [6][256]    u32
  const size_t O_vp  = O_wm3 + 1536;         // [32][2304][64] u32 (18.9MB)
  const size_t needed = (O_vp + 4718592) * 4ull;

  const bool big = ws_size >= needed;
  const int nvp = big ? 576 : 0;

  float* xg  = Wf + O_xg;
  float* HH  = Wf + O_HH;
  float* c0f = Wf + O_c0;
  float* Hlf = Wf + O_Hl;
  float* zf  = Wf + O_z;
  float* fcf = Wf + O_fc;
  unsigned* Vp = W + O_vp;

  // --- merged pre-work ---
  k_pre<<<NPACK + 64 + 7936 + 64, 256, 0, stream>>>(
      Whh, W + O_wl, W + O_wst, W_cn, W + O_wcn, gaze, Wih, bih, bhh, xg, Wh1,
      bh1, Wh2, bh2, Wc1, bc1, Wc2, bc2, HH, c0f);
  // --- fused: LSTM chains + (Vp GEMM + MLP packs) on idle CUs ---
  k_fused<<<64 + nvp + 17, 1024, 0, stream>>>(
      xg, W + O_wst, W + O_wl, c0f, HH, cnn, W + O_wcn, b_cn, Vp, nvp, Wm1,
      W + O_wm1, Wm2, W + O_wm2, Wm3, W + O_wm3, W_lh, W + O_wlh);
  // --- batched attention ---
  k_hl<<<32, 256, 0, stream>>>(HH, W + O_wlh, b_lh, Hlf);
  if (big)
    k_zfin<<<576, 256, 0, stream>>>(Vp, Hlf, w_wt, zf);
  else
    k_att_z<<<576, 256, 0, stream>>>(cnn, W + O_wcn, b_cn, Hlf, w_wt, zf);
  k_att_sf<<<2048, 256, 0, stream>>>(cnn, zf, HH, fcf);
  // --- batched MLP ---
  k_mlp<0><<<128, 256, 0, stream>>>((const void*)fcf, W + O_wm1, bm1, W + O_y1);
  k_mlp<1><<<128, 256, 0, stream>>>((const void*)(W + O_y1), W + O_wm2, bm2, W + O_y2);
  k_mlp3<<<32, 256, 0, stream>>>(W + O_y2, W + O_wm3, bm3, out);
}

// Round 15
// 1072.586 us; speedup vs baseline: 1.4361x; 1.4361x over previous
//
#include <hip/hip_runtime.h>
#include <math.h>

// ---------------------------------------------------------------------------
// SpatialAttentionModel on MI355X.
// R15: verbatim revert to R11 (measured 1071us total; k_fused 937us) after
// three theory-driven regressions (R12-R14). Post-mortem conclusion: the
// LSTM step is LDS-ISSUE-bound (~640 ds_read_b128/CU/step ~= 4500cyc), not
// L2-BW-bound -- byte dieting (e5m2) cannot help; only a structural
// reduction of h-broadcast instructions can (documented for a next round).
// Structure: R6's compiler-streamed LSTM (1024thr, 32 weight pairs in LDS
// stride-36 + 96 pairs streamed as 24 dwordx4 from L2) fused with the Vp
// GEMM (576 blks) + MLP/W_lh packs (17 blks) on the 192 idle CUs.
// ---------------------------------------------------------------------------

typedef _Float16 h2_t __attribute__((ext_vector_type(2)));

#if __has_builtin(__builtin_amdgcn_fdot2)
#define HAVE_FDOT2 1
#else
#define HAVE_FDOT2 0
#endif

__device__ __forceinline__ float dot2(unsigned w, unsigned h, float acc) {
#if HAVE_FDOT2
  return __builtin_amdgcn_fdot2(__builtin_bit_cast(h2_t, w),
                                __builtin_bit_cast(h2_t, h), acc, false);
#else
  h2_t a = __builtin_bit_cast(h2_t, w);
  h2_t b = __builtin_bit_cast(h2_t, h);
  return acc + (float)a[0] * (float)b[0] + (float)a[1] * (float)b[1];
#endif
}

__device__ __forceinline__ unsigned pack2(float a, float b) {
  h2_t p;
  p[0] = (_Float16)a;
  p[1] = (_Float16)b;
  return __builtin_bit_cast(unsigned, p);
}

__device__ __forceinline__ float sigmoid_f(float x) {
  return __builtin_amdgcn_rcpf(1.f + __expf(-x));
}
__device__ __forceinline__ float tanh_f(float x) {
  return 1.f - 2.f * __builtin_amdgcn_rcpf(1.f + __expf(2.f * x));
}

// ---------------------------------------------------------------------------
// Pack Whh:
//  wlds_pack[row*32+p], p<32: pairs 0..31 (static LDS tier)
//  wst  u32[24*1024*4] viewed as uint4[24][1024]: quad (m,row) = pairs
//       32+4m..35+4m of gate row `row` -> one dwordx4 per thread per quad.
__global__ void k_pack_lstm(const float* __restrict__ Whh,
                            unsigned* __restrict__ wlds_pack,
                            unsigned* __restrict__ wst) {
  const int idx = blockIdx.x * 256 + threadIdx.x;  // < 131072
  if (idx < 32768) {
    const int row = idx >> 5, pair = idx & 31;
    wlds_pack[idx] =
        pack2(Whh[row * 256 + 2 * pair], Whh[row * 256 + 2 * pair + 1]);
  } else {
    const int rel = idx - 32768;  // < 98304
    const int m = rel >> 12, row = (rel >> 2) & 1023, d = rel & 3;
    const int pair = 32 + 4 * m + d;
    wst[rel] = pack2(Whh[row * 256 + 2 * pair], Whh[row * 256 + 2 * pair + 1]);
  }
}

// Generic f32 -> packed-f16-pair converter.
__global__ void k_packh2(const float* __restrict__ src,
                         unsigned* __restrict__ dst, int n) {
  const int i = blockIdx.x * 256 + threadIdx.x;
  if (i < n) dst[i] = pack2(src[2 * i], src[2 * i + 1]);
}

// xg[t][b][j] = gaze[b,t,:]·Wih[j,:] + bih[j] + bhh[j]  (gate-major).
__global__ void k_xg(const float* __restrict__ gaze,
                     const float* __restrict__ Wih,
                     const float* __restrict__ bih,
                     const float* __restrict__ bhh,
                     float* __restrict__ xg) {
  const int idx = blockIdx.x * 256 + threadIdx.x;
  if (idx >= 31 * 64 * 1024) return;
  const int j = idx & 1023;
  const int b = (idx >> 10) & 63;
  const int t = idx >> 16;
  const float* gz = gaze + (b * 32 + t) * 3;
  xg[idx] = gz[0] * Wih[j * 3 + 0] + gz[1] * Wih[j * 3 + 1] +
            gz[2] * Wih[j * 3 + 2] + bih[j] + bhh[j];
}

// h0/c0 init.
__global__ void k_init(const float* __restrict__ gaze,
                       const float* __restrict__ Wh1, const float* __restrict__ bh1,
                       const float* __restrict__ Wh2, const float* __restrict__ bh2,
                       const float* __restrict__ Wc1, const float* __restrict__ bc1,
                       const float* __restrict__ Wc2, const float* __restrict__ bc2,
                       float* __restrict__ HH, float* __restrict__ c0) {
  const int b = blockIdx.x;
  const int tid = threadIdx.x;  // 256
  __shared__ float mg[3];
  __shared__ float t1h[256], t1c[256];
  if (tid < 3) {
    float s = 0.f;
    for (int t = 0; t < 32; t++) s += gaze[(b * 32 + t) * 3 + tid];
    mg[tid] = s * (1.f / 32.f);
  }
  __syncthreads();
  {
    float a = mg[0] * Wh1[tid * 3 + 0] + mg[1] * Wh1[tid * 3 + 1] +
              mg[2] * Wh1[tid * 3 + 2] + bh1[tid];
    t1h[tid] = tanhf(a);
    float c = mg[0] * Wc1[tid * 3 + 0] + mg[1] * Wc1[tid * 3 + 1] +
              mg[2] * Wc1[tid * 3 + 2] + bc1[tid];
    t1c[tid] = tanhf(c);
  }
  __syncthreads();
  float s1 = bh2[tid], s2 = bc2[tid];
  for (int k = 0; k < 256; k++) {
    s1 += t1h[k] * Wh2[tid * 256 + k];
    s2 += t1c[k] * Wc2[tid * 256 + k];
  }
  HH[b * 256 + tid] = tanhf(tanhf(s1));
  c0[b * 256 + tid] = tanhf(tanhf(s2));
}

// ---------------------------------------------------------------------------
// Fused kernel (1024 threads/block):
//  blocks [0,64)          : LSTM chains (R6 structure + x4 stream)
//  blocks [64,64+nvp)     : Vp GEMM tiles
//  blocks [64+nvp, +17)   : MLP/W_lh weight packs
__global__ __launch_bounds__(1024) void k_fused(
    const float* __restrict__ xg, const unsigned* __restrict__ wst,
    const unsigned* __restrict__ wlds_pack, const float* __restrict__ c0,
    float* __restrict__ HH, const float* __restrict__ cnn,
    const unsigned* __restrict__ wcn_h2, const float* __restrict__ bcn,
    unsigned* __restrict__ Vp, int nvp, const float* __restrict__ Wm1,
    unsigned* __restrict__ wm1d, const float* __restrict__ Wm2,
    unsigned* __restrict__ wm2d, const float* __restrict__ Wm3,
    unsigned* __restrict__ wm3d, const float* __restrict__ Wlh,
    unsigned* __restrict__ wlhd) {
  const int bid = blockIdx.x;
  const int tid = threadIdx.x;
  __shared__ __align__(16) unsigned smem[38016];  // 152064 B

  if (bid < 64) {
    // ================= LSTM path =================
    const int b = bid;
    unsigned* wlds = smem;                    // [1024*36]
    float* actl = (float*)(smem + 36864);     // [1024]
    unsigned* h2l = smem + 36864 + 1024;      // [128]

    for (int i = tid; i < 1024 * 32; i += 1024) {
      const int row = i >> 5, p = i & 31;
      wlds[row * 36 + p] = wlds_pack[i];
    }

    float cst = (tid < 256) ? c0[b * 256 + tid] : 0.f;
    if (tid < 256) ((_Float16*)h2l)[tid] = (_Float16)HH[b * 256 + tid];
    __syncthreads();

    const unsigned* wA = &wlds[tid * 36];
    const uint4* wstp = (const uint4*)wst + tid;
    const bool is_g = (tid >= 512) & (tid < 768);  // wave-uniform
    float hval = 0.f;

    for (int frame = 0; frame < 32; frame++) {
      const int L = frame ? frame : 1;
      for (int t = 0; t < L; t++) {
        const float xgv = xg[(t * 64 + b) * 1024 + tid];
        float ga0 = 0.f, ga1 = 0.f;
        // ---- LDS tier: pairs 0..31 ----
#pragma unroll
        for (int q = 0; q < 8; q++) {
          const uint4 h4 = *(const uint4*)&h2l[4 * q];
          const uint4 a4 = *(const uint4*)&wA[4 * q];
          if ((q & 1) == 0) {
            ga0 = dot2(a4.x, h4.x, ga0);
            ga0 = dot2(a4.y, h4.y, ga0);
            ga0 = dot2(a4.z, h4.z, ga0);
            ga0 = dot2(a4.w, h4.w, ga0);
          } else {
            ga1 = dot2(a4.x, h4.x, ga1);
            ga1 = dot2(a4.y, h4.y, ga1);
            ga1 = dot2(a4.z, h4.z, ga1);
            ga1 = dot2(a4.w, h4.w, ga1);
          }
        }
        // ---- streamed tier: pairs 32..127 as 24 dwordx4 loads ----
#pragma unroll
        for (int m = 0; m < 24; m++) {
          const uint4 wq = wstp[m << 10];
          const uint4 h4 = *(const uint4*)&h2l[32 + 4 * m];
          if ((m & 1) == 0) {
            ga0 = dot2(wq.x, h4.x, ga0);
            ga0 = dot2(wq.y, h4.y, ga0);
            ga0 = dot2(wq.z, h4.z, ga0);
            ga0 = dot2(wq.w, h4.w, ga0);
          } else {
            ga1 = dot2(wq.x, h4.x, ga1);
            ga1 = dot2(wq.y, h4.y, ga1);
            ga1 = dot2(wq.z, h4.z, ga1);
            ga1 = dot2(wq.w, h4.w, ga1);
          }
        }
        const float g = ga0 + ga1 + xgv;
        const float act = is_g ? tanh_f(g) : sigmoid_f(g);
        actl[tid] = act;
        __syncthreads();  // B1: h2l reads done; acts visible
        if (tid < 256) {
          const float i_ = actl[tid];
          const float f_ = actl[256 + tid];
          const float g_ = actl[512 + tid];
          const float o_ = actl[768 + tid];
          cst = f_ * cst + i_ * g_;
          hval = o_ * tanh_f(cst);
          ((_Float16*)h2l)[tid] = (_Float16)hval;
        }
        __syncthreads();  // B2: h2l ready for next step
      }
      if (tid < 256) HH[((frame + 1) * 64 + b) * 256 + tid] = hval;
    }
  } else if (bid < 64 + nvp) {
    // ================= Vp GEMM path (1024 threads) =================
    const int vb = bid - 64;  // < 576
    const int i = vb / 18, rt = vb - 18 * i;
    const int r0 = rt * 128;
    unsigned* As = smem;                   // 128*132
    unsigned* Bs = smem + 16896;           // 128*132
    float* bcs = (float*)(smem + 33792);   // 128

    for (int idx = tid; idx < 128 * 128; idx += 1024) {
      const int r = idx >> 7, kp = idx & 127;
      const int R = r0 + r;
      const int b = R / 36, g = R - b * 36;
      const float* src = cnn + (((size_t)b * 32 + i) * 36 + g) * 256 + 2 * kp;
      As[r * 132 + kp] = pack2(src[0], src[1]);
    }
    for (int idx = tid; idx < 128 * 128; idx += 1024) {
      const int o = idx >> 7, kp = idx & 127;
      Bs[o * 132 + kp] = wcn_h2[o * 128 + kp];
    }
    if (tid < 128) bcs[tid] = bcn[tid];
    __syncthreads();

    const int ry = tid >> 4, px = tid & 15;  // ry<64
    float acc[2][8];
#pragma unroll
    for (int k = 0; k < 2; k++)
#pragma unroll
      for (int m = 0; m < 8; m++)
        acc[k][m] = bcs[32 * (m >> 1) + 2 * px + (m & 1)];
    for (int kb = 0; kb < 32; kb++) {
      uint4 a4[2], b4[8];
#pragma unroll
      for (int k = 0; k < 2; k++)
        a4[k] = *(const uint4*)&As[(64 * k + ry) * 132 + 4 * kb];
#pragma unroll
      for (int m = 0; m < 8; m++)
        b4[m] = *(const uint4*)&Bs[(32 * (m >> 1) + 2 * px + (m & 1)) * 132 + 4 * kb];
#pragma unroll
      for (int k = 0; k < 2; k++)
#pragma unroll
        for (int m = 0; m < 8; m++) {
          acc[k][m] = dot2(a4[k].x, b4[m].x, acc[k][m]);
          acc[k][m] = dot2(a4[k].y, b4[m].y, acc[k][m]);
          acc[k][m] = dot2(a4[k].z, b4[m].z, acc[k][m]);
          acc[k][m] = dot2(a4[k].w, b4[m].w, acc[k][m]);
        }
    }
#pragma unroll
    for (int k = 0; k < 2; k++) {
      const int R = r0 + 64 * k + ry;
#pragma unroll
      for (int jj = 0; jj < 4; jj++)
        Vp[((size_t)i * 2304 + R) * 64 + 16 * jj + px] =
            pack2(acc[k][2 * jj], acc[k][2 * jj + 1]);
    }
  } else {
    // ================= pack path (17 blocks) =================
    const int pb = bid - 64 - nvp;
    if (pb < 8) {
      const int base = pb * 16384;
      for (int j = tid; j < 16384; j += 1024)
        wm1d[base + j] = pack2(Wm1[2 * (base + j)], Wm1[2 * (base + j) + 1]);
    } else if (pb < 16) {
      const int base = (pb - 8) * 16384;
      for (int j = tid; j < 16384; j += 1024)
        wm2d[base + j] = pack2(Wm2[2 * (base + j)], Wm2[2 * (base + j) + 1]);
    } else {
      for (int j = tid; j < 1536; j += 1024)
        wm3d[j] = pack2(Wm3[2 * j], Wm3[2 * j + 1]);
      for (int j = tid; j < 16384; j += 1024)
        wlhd[j] = pack2(Wlh[2 * j], Wlh[2 * j + 1]);
    }
  }
}

// z finish: z[b,g] = sum_p w[p]*tanh(Hl[i,b,p] + Vp[i,R,p]).
__global__ void k_zfin(const unsigned* __restrict__ Vp,
                       const float* __restrict__ Hl,
                       const float* __restrict__ wwt,
                       float* __restrict__ zbuf) {
  const int bid = blockIdx.x;  // 576
  const int i = bid / 18, rt = bid - 18 * i;
  const int r0 = rt * 128;
  const int tid = threadIdx.x;  // 256
  __shared__ float Hls[5 * 128];
  __shared__ float wws[128];
  __shared__ float zpart[128 * 16];
  const int bmin = r0 / 36;
  for (int idx = tid; idx < 5 * 128; idx += 256) {
    const int bb = bmin + (idx >> 7);
    if (bb < 64) Hls[idx] = Hl[(i * 64 + bb) * 128 + (idx & 127)];
  }
  if (tid < 128) wws[tid] = wwt[tid];
  __syncthreads();
  const int ry = tid >> 4, px = tid & 15;
#pragma unroll
  for (int k = 0; k < 8; k++) {
    const int r = 16 * k + ry;
    const int R = r0 + r;
    const int b = R / 36;
    const unsigned* vr = Vp + ((size_t)i * 2304 + R) * 64;
    const float* Hr = &Hls[(b - bmin) * 128];
    float z = 0.f;
#pragma unroll
    for (int jj = 0; jj < 4; jj++) {
      const int pp = 16 * jj + px;
      const h2_t pr = __builtin_bit_cast(h2_t, vr[pp]);
      z += wws[2 * pp] * tanh_f(Hr[2 * pp] + (float)pr[0]);
      z += wws[2 * pp + 1] * tanh_f(Hr[2 * pp + 1] + (float)pr[1]);
    }
    zpart[r * 16 + px] = z;
  }
  __syncthreads();
  if (tid < 128) {
    float z = 0.f;
#pragma unroll
    for (int x = 0; x < 16; x++) z += zpart[tid * 16 + x];
    const int R = r0 + tid;
    const int b = R / 36, g = R - b * 36;
    zbuf[(i * 64 + b) * 36 + g] = z;
  }
}

// Hl[i][b][p] = HH[i][b]·W_lh[p] + b_lh[p].
__global__ void k_hl(const float* __restrict__ HH,
                     const unsigned* __restrict__ wlh_h2,
                     const float* __restrict__ blh, float* __restrict__ Hl) {
  const int i = blockIdx.x;
  const int tid = threadIdx.x;  // 256
  __shared__ __align__(16) unsigned Ah[64 * 132];
  __shared__ __align__(16) unsigned Bh[128 * 132];
  for (int idx = tid; idx < 64 * 128; idx += 256) {
    const int r = idx >> 7, kp = idx & 127;
    const float* s = HH + ((size_t)(i * 64 + r)) * 256 + 2 * kp;
    Ah[r * 132 + kp] = pack2(s[0], s[1]);
  }
  for (int idx = tid; idx < 128 * 128; idx += 256) {
    const int o = idx >> 7, kp = idx & 127;
    Bh[o * 132 + kp] = wlh_h2[o * 128 + kp];
  }
  __syncthreads();
  const int ry = tid >> 4, px = tid & 15;
  float acc[4][8];
#pragma unroll
  for (int k = 0; k < 4; k++)
#pragma unroll
    for (int j = 0; j < 8; j++) acc[k][j] = 0.f;
  for (int kb = 0; kb < 32; kb++) {
    uint4 a4[4], b4[8];
#pragma unroll
    for (int k = 0; k < 4; k++) a4[k] = *(const uint4*)&Ah[(16 * k + ry) * 132 + 4 * kb];
#pragma unroll
    for (int j = 0; j < 8; j++) b4[j] = *(const uint4*)&Bh[(16 * j + px) * 132 + 4 * kb];
#pragma unroll
    for (int k = 0; k < 4; k++)
#pragma unroll
      for (int j = 0; j < 8; j++) {
        acc[k][j] = dot2(a4[k].x, b4[j].x, acc[k][j]);
        acc[k][j] = dot2(a4[k].y, b4[j].y, acc[k][j]);
        acc[k][j] = dot2(a4[k].z, b4[j].z, acc[k][j]);
        acc[k][j] = dot2(a4[k].w, b4[j].w, acc[k][j]);
      }
  }
#pragma unroll
  for (int k = 0; k < 4; k++)
#pragma unroll
    for (int j = 0; j < 8; j++)
      Hl[(i * 64 + 16 * k + ry) * 128 + 16 * j + px] = acc[k][j] + blh[16 * j + px];
}

// Fallback (small ws): fused Vp GEMM + z.
__global__ void k_att_z(const float* __restrict__ cnn,
                        const unsigned* __restrict__ wcn_h2,
                        const float* __restrict__ bcn,
                        const float* __restrict__ Hl,
                        const float* __restrict__ wwt,
                        float* __restrict__ zbuf) {
  const int bid = blockIdx.x;  // 576
  const int i = bid / 18, rt = bid - 18 * i;
  const int tid = threadIdx.x;  // 256
  const int r0 = rt * 128;
  __shared__ __align__(16) unsigned As[128 * 132];
  __shared__ __align__(16) unsigned Bs[128 * 132];
  __shared__ float zpart[128 * 16];
  __shared__ float Hls[5 * 128];
  __shared__ float wws[128];
  __shared__ float bcs[128];

  for (int idx = tid; idx < 128 * 128; idx += 256) {
    const int r = idx >> 7, kp = idx & 127;
    const int R = r0 + r;
    const int b = R / 36, g = R - b * 36;
    const float* src = cnn + (((size_t)b * 32 + i) * 36 + g) * 256 + 2 * kp;
    As[r * 132 + kp] = pack2(src[0], src[1]);
  }
  for (int idx = tid; idx < 128 * 128; idx += 256) {
    const int o = idx >> 7, kp = idx & 127;
    Bs[o * 132 + kp] = wcn_h2[o * 128 + kp];
  }
  const int bmin = r0 / 36;
  for (int idx = tid; idx < 5 * 128; idx += 256) {
    const int bb = bmin + (idx >> 7);
    if (bb < 64) Hls[idx] = Hl[(i * 64 + bb) * 128 + (idx & 127)];
  }
  if (tid < 128) {
    wws[tid] = wwt[tid];
    bcs[tid] = bcn[tid];
  }
  __syncthreads();

  const int ry = tid >> 4, px = tid & 15;
  float acc[8][8];
#pragma unroll
  for (int k = 0; k < 8; k++)
#pragma unroll
    for (int j = 0; j < 8; j++) acc[k][j] = bcs[16 * j + px];
  for (int kb = 0; kb < 32; kb++) {
    uint4 a4[8], b4[8];
#pragma unroll
    for (int k = 0; k < 8; k++) a4[k] = *(const uint4*)&As[(16 * k + ry) * 132 + 4 * kb];
#pragma unroll
    for (int j = 0; j < 8; j++) b4[j] = *(const uint4*)&Bs[(16 * j + px) * 132 + 4 * kb];
#pragma unroll
    for (int k = 0; k < 8; k++)
#pragma unroll
      for (int j = 0; j < 8; j++) {
        acc[k][j] = dot2(a4[k].x, b4[j].x, acc[k][j]);
        acc[k][j] = dot2(a4[k].y, b4[j].y, acc[k][j]);
        acc[k][j] = dot2(a4[k].z, b4[j].z, acc[k][j]);
        acc[k][j] = dot2(a4[k].w, b4[j].w, acc[k][j]);
      }
  }
#pragma unroll
  for (int k = 0; k < 8; k++) {
    const int r = 16 * k + ry;
    const int R = r0 + r;
    const int b = R / 36;
    const float* HlRow = &Hls[(b - bmin) * 128];
    float zp = 0.f;
#pragma unroll
    for (int j = 0; j < 8; j++) {
      const int po = 16 * j + px;
      zp += wws[po] * tanh_f(HlRow[po] + acc[k][j]);
    }
    zpart[r * 16 + px] = zp;
  }
  __syncthreads();
  if (tid < 128) {
    float z = 0.f;
#pragma unroll
    for (int x = 0; x < 16; x++) z += zpart[tid * 16 + x];
    const int R = r0 + tid;
    const int b = R / 36, g = R - b * 36;
    zbuf[(i * 64 + b) * 36 + g] = z;
  }
}

// Scrambled softmax + weighted V sum; builds fc = [spatial_feat | h_next].
__global__ void k_att_sf(const float* __restrict__ cnn,
                         const float* __restrict__ zbuf,
                         const float* __restrict__ HH,
                         float* __restrict__ fc) {
  const int bid = blockIdx.x;  // 2048
  const int i = bid >> 6, b = bid & 63;
  const int tid = threadIdx.x;  // 256
  __shared__ float zl[36];
  __shared__ float el[40];
  __shared__ float red[1];
  if (tid < 36) {
    const int idx = b * 36 + tid;
    zl[tid] = zbuf[(i * 64 + (idx & 63)) * 36 + (idx >> 6)];
  }
  __syncthreads();
  if (tid == 0) {
    float m = zl[0];
    for (int g = 1; g < 36; g++) m = fmaxf(m, zl[g]);
    float s = 0.f;
    for (int g = 0; g < 36; g++) {
      const float e = __expf(zl[g] - m);
      el[g] = e;
      s += e;
    }
    red[0] = 1.f / s;
  }
  __syncthreads();
  const float inv = red[0];
  float accv = 0.f;
  const float* Vb = cnn + (((size_t)b * 32 + i) * 36) * 256 + tid;
#pragma unroll 4
  for (int g = 0; g < 36; g++) accv += el[g] * Vb[g * 256];
  fc[(size_t)bid * 512 + tid] = accv * inv;
  fc[(size_t)bid * 512 + 256 + tid] = HH[((i + 1) * 64 + b) * 256 + tid];
}

// MLP layers 1/2.
template <int SRCMODE>
__global__ void k_mlp(const void* __restrict__ src,
                      const unsigned* __restrict__ wh2,
                      const float* __restrict__ bias,
                      unsigned* __restrict__ dst) {
  const int bid = blockIdx.x;  // 128
  const int nb = bid >> 2, ob = bid & 3;
  const int n0 = nb * 64, o0 = ob * 128;
  const int tid = threadIdx.x;
  __shared__ __align__(16) unsigned As[64 * 132];
  __shared__ __align__(16) unsigned Bs[128 * 132];
  const int ry = tid >> 4, px = tid & 15;
  float acc[4][8];
#pragma unroll
  for (int k = 0; k < 4; k++)
#pragma unroll
    for (int m = 0; m < 8; m++)
      acc[k][m] = bias[o0 + 32 * (m >> 1) + 2 * px + (m & 1)];
  for (int kc = 0; kc < 2; kc++) {
    __syncthreads();
    for (int idx = tid; idx < 64 * 128; idx += 256) {
      const int r = idx >> 7, kp = idx & 127;
      if (SRCMODE == 0) {
        const float* s = (const float*)src + ((size_t)(n0 + r)) * 512 + kc * 256 + 2 * kp;
        As[r * 132 + kp] = pack2(s[0], s[1]);
      } else {
        As[r * 132 + kp] = ((const unsigned*)src)[((size_t)(n0 + r)) * 256 + kc * 128 + kp];
      }
    }
    for (int idx = tid; idx < 128 * 128; idx += 256) {
      const int o = idx >> 7, kp = idx & 127;
      Bs[o * 132 + kp] = wh2[((size_t)(o0 + o)) * 256 + kc * 128 + kp];
    }
    __syncthreads();
    for (int kb = 0; kb < 32; kb++) {
      uint4 a4[4], b4[8];
#pragma unroll
      for (int k = 0; k < 4; k++)
        a4[k] = *(const uint4*)&As[(16 * k + ry) * 132 + 4 * kb];
#pragma unroll
      for (int m = 0; m < 8; m++)
        b4[m] = *(const uint4*)&Bs[(32 * (m >> 1) + 2 * px + (m & 1)) * 132 + 4 * kb];
#pragma unroll
      for (int k = 0; k < 4; k++)
#pragma unroll
        for (int m = 0; m < 8; m++) {
          acc[k][m] = dot2(a4[k].x, b4[m].x, acc[k][m]);
          acc[k][m] = dot2(a4[k].y, b4[m].y, acc[k][m]);
          acc[k][m] = dot2(a4[k].z, b4[m].z, acc[k][m]);
          acc[k][m] = dot2(a4[k].w, b4[m].w, acc[k][m]);
        }
    }
  }
#pragma unroll
  for (int k = 0; k < 4; k++) {
    const int n = n0 + 16 * k + ry;
#pragma unroll
    for (int j = 0; j < 4; j++)
      dst[(size_t)n * 256 + (o0 >> 1) + 16 * j + px] =
          pack2(acc[k][2 * j], acc[k][2 * j + 1]);
  }
}

// Final layer: (2048,512) -> 6 classes.
__global__ void k_mlp3(const unsigned* __restrict__ y2h2,
                       const unsigned* __restrict__ wm3h2,
                       const float* __restrict__ bm3,
                       float* __restrict__ out) {
  const int nb = blockIdx.x;  // 32
  const int tid = threadIdx.x;
  __shared__ __align__(16) unsigned Ys[64 * 256];
  __shared__ __align__(16) unsigned Ws[6 * 256];
  for (int idx = tid; idx < 64 * 256; idx += 256)
    Ys[idx] = y2h2[(size_t)nb * 64 * 256 + idx];
  for (int idx = tid; idx < 6 * 256; idx += 256) Ws[idx] = wm3h2[idx];
  __syncthreads();
  for (int u = 0; u < 2; u++) {
    const int idx = tid + u * 256;
    if (idx < 384) {
      const int nl = idx / 6, c = idx - 6 * nl;
      float a0 = 0.f, a1 = 0.f;
#pragma unroll
      for (int kq = 0; kq < 64; kq++) {
        const uint4 y4 = *(const uint4*)&Ys[nl * 256 + 4 * kq];
        const uint4 w4 = *(const uint4*)&Ws[c * 256 + 4 * kq];
        a0 = dot2(y4.x, w4.x, a0);
        a1 = dot2(y4.y, w4.y, a1);
        a0 = dot2(y4.z, w4.z, a0);
        a1 = dot2(y4.w, w4.w, a1);
      }
      out[(size_t)(nb * 64 + nl) * 6 + c] = a0 + a1 + bm3[c];
    }
  }
}

// ---------------------------------------------------------------------------
extern "C" void kernel_launch(void* const* d_in, const int* in_sizes, int n_in,
                              void* d_out, int out_size, void* d_ws,
                              size_t ws_size, hipStream_t stream) {
  (void)in_sizes; (void)n_in; (void)out_size;
  const float* cnn  = (const float*)d_in[0];
  const float* gaze = (const float*)d_in[1];
  const float* W_lh = (const float*)d_in[2];
  const float* b_lh = (const float*)d_in[3];
  const float* W_cn = (const float*)d_in[4];
  const float* b_cn = (const float*)d_in[5];
  const float* w_wt = (const float*)d_in[6];
  const float* Wih  = (const float*)d_in[7];
  const float* Whh  = (const float*)d_in[8];
  const float* bih  = (const float*)d_in[9];
  const float* bhh  = (const float*)d_in[10];
  const float* Wh1  = (const float*)d_in[11];
  const float* bh1  = (const float*)d_in[12];
  const float* Wh2  = (const float*)d_in[13];
  const float* bh2  = (const float*)d_in[14];
  const float* Wc1  = (const float*)d_in[15];
  const float* bc1  = (const float*)d_in[16];
  const float* Wc2  = (const float*)d_in[17];
  const float* bc2  = (const float*)d_in[18];
  const float* Wm1  = (const float*)d_in[19];
  const float* bm1  = (const float*)d_in[20];
  const float* Wm2  = (const float*)d_in[21];
  const float* bm2  = (const float*)d_in[22];
  const float* Wm3  = (const float*)d_in[23];
  const float* bm3  = (const float*)d_in[24];
  float* out = (float*)d_out;

  unsigned* W = (unsigned*)d_ws;
  float* Wf = (float*)d_ws;
  // workspace offsets in dwords
  const size_t O_xg  = 0;                    // [31][64][1024] f32
  const size_t O_wl  = 2031616;              // [1024][32]  u32
  const size_t O_wst = O_wl + 32768;         // [24][1024] uint4 = 98304 u32
  const size_t O_HH  = O_wst + 98304;        // [33][64][256] f32
  const size_t O_c0  = O_HH + 540672;        // [64][256]   f32
  const size_t O_Hl  = O_c0 + 16384;         // [32][64][128] f32
  const size_t O_z   = O_Hl + 262144;        // [32][64][36] f32
  const size_t O_fc  = O_z + 73728;          // [2048][512] f32
  const size_t O_y1  = O_fc + 1048576;       // [2048][256] u32
  const size_t O_y2  = O_y1 + 524288;        // [2048][256] u32
  const size_t O_wcn = O_y2 + 524288;        // [128][128]  u32
  const size_t O_wlh = O_wcn + 16384;        // [128][128]  u32
  const size_t O_wm1 = O_wlh + 16384;        // [512][256]  u32
  const size_t O_wm2 = O_wm1 + 131072;
  const size_t O_wm3 = O_wm2 + 131072;       // [6][256]    u32
  const size_t O_vp  = O_wm3 + 1536;         // [32][2304][64] u32 (18.9MB)
  const size_t needed = (O_vp + 4718592) * 4ull;

  const bool big = ws_size >= needed;
  const int nvp = big ? 576 : 0;

  float* xg  = Wf + O_xg;
  float* HH  = Wf + O_HH;
  float* c0f = Wf + O_c0;
  float* Hlf = Wf + O_Hl;
  float* zf  = Wf + O_z;
  float* fcf = Wf + O_fc;
  unsigned* Vp = W + O_vp;

  // --- upfront (LSTM/Vp dependencies) ---
  k_pack_lstm<<<512, 256, 0, stream>>>(Whh, W + O_wl, W + O_wst);
  k_packh2<<<64, 256, 0, stream>>>(W_cn, W + O_wcn, 16384);
  k_xg<<<7936, 256, 0, stream>>>(gaze, Wih, bih, bhh, xg);
  k_init<<<64, 256, 0, stream>>>(gaze, Wh1, bh1, Wh2, bh2, Wc1, bc1, Wc2, bc2,
                                 HH, c0f);
  // --- fused: LSTM chains + (Vp GEMM + MLP packs) on idle CUs ---
  k_fused<<<64 + nvp + 17, 1024, 0, stream>>>(
      xg, W + O_wst, W + O_wl, c0f, HH, cnn, W + O_wcn, b_cn, Vp, nvp, Wm1,
      W + O_wm1, Wm2, W + O_wm2, Wm3, W + O_wm3, W_lh, W + O_wlh);
  // --- batched attention ---
  k_hl<<<32, 256, 0, stream>>>(HH, W + O_wlh, b_lh, Hlf);
  if (big)
    k_zfin<<<576, 256, 0, stream>>>(Vp, Hlf, w_wt, zf);
  else
    k_att_z<<<576, 256, 0, stream>>>(cnn, W + O_wcn, b_cn, Hlf, w_wt, zf);
  k_att_sf<<<2048, 256, 0, stream>>>(cnn, zf, HH, fcf);
  // --- batched MLP ---
  k_mlp<0><<<128, 256, 0, stream>>>((const void*)fcf, W + O_wm1, bm1, W + O_y1);
  k_mlp<1><<<128, 256, 0, stream>>>((const void*)(W + O_y1), W + O_wm2, bm2, W + O_y2);
  k_mlp3<<<32, 256, 0, stream>>>(W + O_y2, W + O_wm3, bm3, out);
}